// Round 4
// baseline (434.463 us; speedup 1.0000x reference)
//
#include <hip/hip_runtime.h>
#include <math.h>

#define B_ 64
#define T_ 4096
#define D_ 256
#define U_ 64
#define TM 128           // rows per logits block (4 waves x 2 strips x 16)
#define TC 256           // t-chunk per context block

typedef float f32x4 __attribute__((ext_vector_type(4)));
typedef short bf16x8 __attribute__((ext_vector_type(8)));

__device__ __forceinline__ unsigned short f2bf_rne(float f) {
    unsigned u = __float_as_uint(f);
    unsigned r = u + 0x7fffu + ((u >> 16) & 1u);
    return (unsigned short)(r >> 16);
}
__device__ __forceinline__ float bfbits2f(unsigned short s) {
    return __uint_as_float(((unsigned)s) << 16);
}

// Pack W [D,U] fp32 into MFMA B-fragment order, split hi/lo bf16.
// Fragment (ks,nt,lane,j): value = W[k = ks*32 + (lane>>4)*8 + j][n = nt*16 + (lane&15)]
__global__ __launch_bounds__(256) void wprep_kernel(
    const float* __restrict__ W, unsigned short* __restrict__ whi,
    unsigned short* __restrict__ wlo)
{
    int fi = blockIdx.x * 256 + threadIdx.x;   // 0..16383, grid=64
    int j    = fi & 7;
    int lane = (fi >> 3) & 63;
    int tile = fi >> 9;            // 0..31
    int nt = tile & 3, ks = tile >> 2;
    int k = ks * 32 + (lane >> 4) * 8 + j;
    int n = nt * 16 + (lane & 15);
    float w = W[k * U_ + n];
    unsigned short hi = f2bf_rne(w);
    unsigned short lo = f2bf_rne(w - bfbits2f(hi));
    whi[fi] = hi;
    wlo[fi] = lo;
}

// Pass 1: e[b,t] = exp( tanh(x@W + b) @ u ), unnormalized (logit bounded by
// sum|u| ~ 9.7, exp safe in fp32). Also:
//  - stashes bf16(x) to xbf for pass 3 (half the bytes, likely L3-resident)
//  - writes deterministic per-block partial sums Zp[block] (no atomics)
// W fragments (hi+lo, 64KB) staged once in LDS. 4 waves, 2 row-strips each.
__global__ __launch_bounds__(256) void logits_mfma(
    const float* __restrict__ x, const unsigned short* __restrict__ whi,
    const unsigned short* __restrict__ wlo, const float* __restrict__ bias,
    const float* __restrict__ uvec, float* __restrict__ wts,
    unsigned short* __restrict__ xbf, float* __restrict__ Zp)
{
    __shared__ unsigned short Bh[16384];   // 32 KB
    __shared__ unsigned short Bl[16384];   // 32 KB
    __shared__ float zred[4];

    int tid = threadIdx.x;
    {
        const uint4* sh = (const uint4*)whi;
        const uint4* sl = (const uint4*)wlo;
        uint4* dh = (uint4*)Bh;
        uint4* dl = (uint4*)Bl;
#pragma unroll
        for (int i = 0; i < 8; ++i) {
            dh[tid + i * 256] = sh[tid + i * 256];
            dl[tid + i * 256] = sl[tid + i * 256];
        }
    }
    __syncthreads();

    int lane = tid & 63, wid = tid >> 6;
    int q = lane >> 4, r = lane & 15;
    size_t R0 = (size_t)blockIdx.x * TM;
    size_t row0 = R0 + wid * 16 + r;
    size_t row1 = row0 + 64;
    const float* x0 = x + row0 * D_;
    const float* x1 = x + row1 * D_;
    unsigned short* xo0 = xbf + row0 * D_;
    unsigned short* xo1 = xbf + row1 * D_;

    f32x4 acc0[4], acc1[4];
#pragma unroll
    for (int nt = 0; nt < 4; ++nt) {
        acc0[nt] = (f32x4){0.f, 0.f, 0.f, 0.f};
        acc1[nt] = (f32x4){0.f, 0.f, 0.f, 0.f};
    }

    const bf16x8* BhV = (const bf16x8*)Bh;
    const bf16x8* BlV = (const bf16x8*)Bl;

#pragma unroll 4
    for (int ks = 0; ks < 8; ++ks) {
        int k0 = ks * 32 + q * 8;
        float4 va0 = *(const float4*)(x0 + k0);
        float4 vb0 = *(const float4*)(x0 + k0 + 4);
        float4 va1 = *(const float4*)(x1 + k0);
        float4 vb1 = *(const float4*)(x1 + k0 + 4);
        float f0[8] = {va0.x, va0.y, va0.z, va0.w, vb0.x, vb0.y, vb0.z, vb0.w};
        float f1[8] = {va1.x, va1.y, va1.z, va1.w, vb1.x, vb1.y, vb1.z, vb1.w};
        union { bf16x8 v; unsigned short s[8]; uint4 u; } h0, l0, h1, l1;
#pragma unroll
        for (int j = 0; j < 8; ++j) {
            unsigned short a = f2bf_rne(f0[j]);
            h0.s[j] = a;
            l0.s[j] = f2bf_rne(f0[j] - bfbits2f(a));
            unsigned short c = f2bf_rne(f1[j]);
            h1.s[j] = c;
            l1.s[j] = f2bf_rne(f1[j] - bfbits2f(c));
        }
        *(uint4*)(xo0 + k0) = h0.u;
        *(uint4*)(xo1 + k0) = h1.u;
#pragma unroll
        for (int nt = 0; nt < 4; ++nt) {
            bf16x8 bh = BhV[(ks * 4 + nt) * 64 + lane];
            bf16x8 bl = BlV[(ks * 4 + nt) * 64 + lane];
            acc0[nt] = __builtin_amdgcn_mfma_f32_16x16x32_bf16(h0.v, bh, acc0[nt], 0, 0, 0);
            acc0[nt] = __builtin_amdgcn_mfma_f32_16x16x32_bf16(h0.v, bl, acc0[nt], 0, 0, 0);
            acc0[nt] = __builtin_amdgcn_mfma_f32_16x16x32_bf16(l0.v, bh, acc0[nt], 0, 0, 0);
            acc1[nt] = __builtin_amdgcn_mfma_f32_16x16x32_bf16(h1.v, bh, acc1[nt], 0, 0, 0);
            acc1[nt] = __builtin_amdgcn_mfma_f32_16x16x32_bf16(h1.v, bl, acc1[nt], 0, 0, 0);
            acc1[nt] = __builtin_amdgcn_mfma_f32_16x16x32_bf16(l1.v, bh, acc1[nt], 0, 0, 0);
        }
    }

    // Epilogue per strip: p = tanh(acc+bias)@u, reduce over 16 n-lanes,
    // e = exp(p) -> wts; accumulate block partial Z.
    float zsum = 0.f;
#pragma unroll
    for (int s = 0; s < 2; ++s) {
        f32x4* A = s ? acc1 : acc0;
        float p0 = 0.f, p1 = 0.f, p2 = 0.f, p3 = 0.f;
#pragma unroll
        for (int nt = 0; nt < 4; ++nt) {
            int col = nt * 16 + r;
            float bv = bias[col], uv = uvec[col];
            float s0 = A[nt][0] + bv, s1 = A[nt][1] + bv,
                  s2 = A[nt][2] + bv, s3 = A[nt][3] + bv;
            p0 = fmaf(1.f - 2.f / (__expf(2.f * s0) + 1.f), uv, p0);
            p1 = fmaf(1.f - 2.f / (__expf(2.f * s1) + 1.f), uv, p1);
            p2 = fmaf(1.f - 2.f / (__expf(2.f * s2) + 1.f), uv, p2);
            p3 = fmaf(1.f - 2.f / (__expf(2.f * s3) + 1.f), uv, p3);
        }
#pragma unroll
        for (int off = 1; off < 16; off <<= 1) {
            p0 += __shfl_xor(p0, off, 64);
            p1 += __shfl_xor(p1, off, 64);
            p2 += __shfl_xor(p2, off, 64);
            p3 += __shfl_xor(p3, off, 64);
        }
        float e0 = __expf(p0), e1 = __expf(p1), e2 = __expf(p2), e3 = __expf(p3);
        if (r == 0) {
            float4 o = {e0, e1, e2, e3};
            *(float4*)(wts + R0 + s * 64 + wid * 16 + q * 4) = o;
        }
        zsum += (e0 + e1) + (e2 + e3);
    }
    // sum across the 4 q-groups (values equal within a 16-lane group)
    zsum += __shfl_xor(zsum, 16, 64);
    zsum += __shfl_xor(zsum, 32, 64);
    if (lane == 0) zred[wid] = zsum;
    __syncthreads();
    if (tid == 0) Zp[blockIdx.x] = (zred[0] + zred[1]) + (zred[2] + zred[3]);
}

// Pass 3: Z = sum(Zp); normalize weights in place; context += w*x (bf16 x).
// Thread (ph=tid>>5, colg=tid&31): rows t0+i+ph, 8 d-columns colg*8..+8.
__global__ __launch_bounds__(256) void context_kernel(
    const unsigned short* __restrict__ xbf, float* __restrict__ wts,
    const float* __restrict__ Zp, float* __restrict__ ctx)
{
    int b = blockIdx.y;
    int t0 = blockIdx.x * TC;
    int tid = threadIdx.x;
    int colg = tid & 31, ph = tid >> 5;

    float Z = 0.f;
#pragma unroll
    for (int i = 0; i < T_ / TM; ++i) Z += Zp[b * (T_ / TM) + i];   // uniform s_loads
    float invZ = 1.f / Z;

    __shared__ float wsh[TC];
    float e = wts[(size_t)b * T_ + t0 + tid];
    wsh[tid] = e;
    wts[(size_t)b * T_ + t0 + tid] = e * invZ;   // final normalized weight
    __syncthreads();

    const unsigned short* xb = xbf + ((size_t)b * T_ + t0) * D_;
    float acc[8];
#pragma unroll
    for (int j = 0; j < 8; ++j) acc[j] = 0.f;

#pragma unroll 4
    for (int i = 0; i < TC; i += 8) {
        int row = i + ph;
        float w = wsh[row];
        union { uint4 u; unsigned short s[8]; } v;
        v.u = *(const uint4*)(xb + (size_t)row * D_ + colg * 8);
#pragma unroll
        for (int j = 0; j < 8; ++j)
            acc[j] = fmaf(w, bfbits2f(v.s[j]), acc[j]);
    }

    __shared__ float red[8 * 256];
#pragma unroll
    for (int j = 0; j < 8; ++j) red[ph * 256 + colg * 8 + j] = acc[j];
    __syncthreads();
    float ssum = 0.f;
#pragma unroll
    for (int p = 0; p < 8; ++p) ssum += red[p * 256 + tid];
    atomicAdd(&ctx[b * D_ + tid], ssum * invZ);
}

extern "C" void kernel_launch(void* const* d_in, const int* in_sizes, int n_in,
                              void* d_out, int out_size, void* d_ws, size_t ws_size,
                              hipStream_t stream) {
    const float* x    = (const float*)d_in[0];   // [B,T,D]
    const float* W    = (const float*)d_in[1];   // [D,U]
    const float* bias = (const float*)d_in[2];   // [U]
    const float* uvec = (const float*)d_in[3];   // [U,1]

    float* out = (float*)d_out;
    float* ctx = out;            // context: B*D floats
    float* wts = out + B_ * D_;  // attention weights: B*T floats (unnorm e between passes)

    unsigned short* whi = (unsigned short*)d_ws;               // 32 KB
    unsigned short* wlo = whi + D_ * U_;                       // 32 KB
    unsigned short* xbf = wlo + D_ * U_;                       // 134 MB bf16 x stash
    float* Zp = (float*)(xbf + (size_t)B_ * T_ * D_);          // B*T/TM partials

    hipMemsetAsync(ctx, 0, B_ * D_ * sizeof(float), stream);

    wprep_kernel<<<D_ * U_ / 256, 256, 0, stream>>>(W, whi, wlo);
    logits_mfma<<<(B_ * T_) / TM, 256, 0, stream>>>(x, whi, wlo, bias, uvec, wts, xbf, Zp);
    context_kernel<<<dim3(T_ / TC, B_), 256, 0, stream>>>(xbf, wts, Zp, ctx);
}